// Round 9
// baseline (329.323 us; speedup 1.0000x reference)
//
#include <hip/hip_runtime.h>

#define HID 128
#define PTS 32
#define KP  136   // sB k-row stride in bf16 units (128 + 8 pad)
#define FRAGS_PER_W 2048           // 8 mtg * 4 ks * 64 lanes
#define WS_ELEMS (FRAGS_PER_W * 8) // ushorts per (w, hi/lo) plane

typedef float v4f __attribute__((ext_vector_type(4)));
typedef short s8v __attribute__((ext_vector_type(8)));          // 8 bf16 (MFMA A/B frag)

__device__ __forceinline__ unsigned short f2bf(float f) {       // RNE (prep only)
    unsigned u = __builtin_bit_cast(unsigned, f);
    u = (u + 0x7FFFu + ((u >> 16) & 1u)) >> 16;
    return (unsigned short)u;
}
__device__ __forceinline__ float bf2f(unsigned short h) {
    unsigned u = ((unsigned)h) << 16;
    return __builtin_bit_cast(float, u);
}

// --- packed fp32 -> 2x bf16 (RNE), 1 instr on gfx950 ---
#if __has_builtin(__builtin_amdgcn_cvt_pk_bf16_f32)
typedef __bf16 bf16x2 __attribute__((ext_vector_type(2)));
__device__ __forceinline__ unsigned pk2(float f0, float f1) {   // (bf(f1)<<16)|bf(f0)
    return __builtin_bit_cast(unsigned, __builtin_amdgcn_cvt_pk_bf16_f32(f0, f1));
}
#else
__device__ __forceinline__ unsigned pk2(float f0, float f1) {
    unsigned u0 = __builtin_bit_cast(unsigned, f0);
    unsigned u1 = __builtin_bit_cast(unsigned, f1);
    u0 += 0x7FFFu + ((u0 >> 16) & 1u);
    u1 += 0x7FFFu + ((u1 >> 16) & 1u);
    return __builtin_amdgcn_perm(u1, u0, 0x07060302u);
}
#endif

__device__ __forceinline__ float expf2x(float x) {              // exp(2x) via v_exp
#if __has_builtin(__builtin_amdgcn_exp2f)
    return __builtin_amdgcn_exp2f(x * 2.885390081777927f);      // 2*log2(e)
#else
    return __expf(2.0f * x);
#endif
}

// 16-wide staged tanh: all exps issued back-to-back, then all rcps -> max ILP
// (round 8's per-vector chaining serialized the quarter-rate trans ops).
__device__ __forceinline__ void tanh16(const v4f z[4], v4f a[4]) {
    v4f e[4];
    #pragma unroll
    for (int m = 0; m < 4; ++m)
        #pragma unroll
        for (int i = 0; i < 4; ++i)
            e[m][i] = expf2x(z[m][i]);
    v4f d[4];
    #pragma unroll
    for (int m = 0; m < 4; ++m) d[m] = e[m] + 1.0f;
    v4f r[4];
    #pragma unroll
    for (int m = 0; m < 4; ++m)
        #pragma unroll
        for (int i = 0; i < 4; ++i)
            r[m][i] = __builtin_amdgcn_rcpf(d[m][i]);
    #pragma unroll
    for (int m = 0; m < 4; ++m) a[m] = 1.0f - 2.0f * r[m];
}

// One-time: W1/W2 -> RNE-split bf16 A-fragments, frag-linear in d_ws; zero d_out.
// ws plane order: [W1hi][W1lo][W2hi][W2lo]; frag idx r = mtg*256 + ks*64 + lane.
__global__ __launch_bounds__(256) void prep_w_kernel(
    const float* __restrict__ W1, const float* __restrict__ W2,
    unsigned short* __restrict__ ws, float* __restrict__ out)
{
    if (blockIdx.x == 0 && threadIdx.x < 2) out[threadIdx.x] = 0.0f;
    const int t = blockIdx.x * 256 + threadIdx.x;   // 0..4095
    const int w = t >> 11;
    const int r = t & 2047;
    const int mtg = r >> 8;
    const int ks = (r >> 6) & 3;
    const int lane = r & 63;
    const int m = mtg * 16 + (lane & 15);
    const int kb = ks * 32 + (lane >> 4) * 8;
    const float* W = w ? W2 : W1;
    s8v hv, lv;
    #pragma unroll
    for (int i = 0; i < 8; ++i) {
        float f = W[(kb + i) * HID + m];            // A[m][k] = W[k][m]
        unsigned short hh = f2bf(f);
        hv[i] = (short)hh;
        lv[i] = (short)f2bf(f - bf2f(hh));
    }
    *(s8v*)&ws[((size_t)(w * 2 + 0) * FRAGS_PER_W + r) * 8] = hv;
    *(s8v*)&ws[((size_t)(w * 2 + 1) * FRAGS_PER_W + r) * 8] = lv;
}

// Fused interior+boundary. Blocks [0,gi): interior (lap readout); rest: boundary.
// One block = 32 points, 4 channels (0=val,1=dx,2=dy,3=lap).
// 2-product split-bf16 MFMA (W = whi+wlo exact to 2^-18, register-resident),
// activations single RNE bf16 in LDS. Readout fused into the L1 epilogue
// (register dot with W3 + quad shuffles + 128B LDS mh-exchange): no L1 store,
// no readout phase, 4 barriers total. W stage-0 prefetches hoisted over barriers.
// Wave grid: (j-half mh) x (p-half pt). C/D layout (m89): col=lane&15, row=quad*4+reg.
__global__ __launch_bounds__(256, 4) void pinn_mfma_kernel(
    const float* __restrict__ xy_int, const float* __restrict__ f_t,
    const float* __restrict__ xy_bd, const float* __restrict__ g_t,
    const float* __restrict__ W0, const float* __restrict__ b0,
    const float* __restrict__ b1, const float* __restrict__ b2,
    const float* __restrict__ W3, const float* __restrict__ b3,
    const unsigned short* __restrict__ ws, float* __restrict__ out,
    int gi, float scale_int, float scale_bd)
{
    extern __shared__ char smem_raw[];
    unsigned short* sBh = (unsigned short*)smem_raw;     // [4*32][KP] bf16 (RNE)
    float* sPart = (float*)(sBh + 4 * 32 * KP);          // [PTS] cross-mh partials

    const bool is_bd = (int)blockIdx.x >= gi;
    const float* __restrict__ xy  = is_bd ? xy_bd : xy_int;
    const float* __restrict__ tgt = is_bd ? g_t : f_t;
    const int pbase = (is_bd ? ((int)blockIdx.x - gi) : (int)blockIdx.x) * PTS;

    const int tid   = threadIdx.x;
    const int lane  = tid & 63;
    const int wave  = tid >> 6;
    const int l15   = lane & 15;
    const int quad  = lane >> 4;
    const int mh    = wave & 1;     // j-half: m-tiles mh*4..mh*4+3
    const int pt    = wave >> 1;    // p-half: cols pt*16..pt*16+15

    const unsigned short* ws1h = ws;
    const unsigned short* ws1l = ws + WS_ELEMS;
    const unsigned short* ws2h = ws + 2 * WS_ELEMS;
    const unsigned short* ws2l = ws + 3 * WS_ELEMS;

    // ---- W1 stage-0 prefetch FIRST: L2 latency hides under layer-0 math ----
    s8v whi[2][4], wlo[2][4];       // [buf][mt], double-buffered per ks stage
    #pragma unroll
    for (int mt = 0; mt < 4; ++mt) {
        const int idx = (mh * 4 + mt) * 256 + lane;       // ks = 0
        whi[0][mt] = *(const s8v*)&ws1h[(size_t)idx * 8];
        wlo[0][mt] = *(const s8v*)&ws1l[(size_t)idx * 8];
    }
    // readout weights, register-resident for the fused epilogue
    v4f w3v[4];
    #pragma unroll
    for (int mt = 0; mt < 4; ++mt)
        w3v[mt] = *(const v4f*)&W3[(mh * 4 + mt) * 16 + quad * 4];

    // ---- layer 0: 2 -> 128, staged-ILP VALU, RNE-bf16 store into sB ----
    {
        const int tj = tid & 31, tp = tid >> 5;
        const int j0 = tj * 4, p0 = tp * 4;
        v4f xv, yv;
        #pragma unroll
        for (int pp = 0; pp < 4; ++pp) {
            const float2 t2 = ((const float2*)xy)[pbase + p0 + pp];
            xv[pp] = t2.x; yv[pp] = t2.y;
        }
        float wx[4], wy[4], bb[4], n2[4];
        #pragma unroll
        for (int jj = 0; jj < 4; ++jj) {
            wx[jj] = W0[j0 + jj];
            wy[jj] = W0[HID + j0 + jj];
            bb[jj] = b0[j0 + jj];
            n2[jj] = -2.0f * fmaf(wx[jj], wx[jj], wy[jj] * wy[jj]);
        }
        v4f z[4], a[4];
        #pragma unroll
        for (int jj = 0; jj < 4; ++jj)
            z[jj] = xv * wx[jj] + yv * wy[jj] + bb[jj];
        tanh16(z, a);
        v4f chv[4][4];                          // [c][jj], vector over pp
        #pragma unroll
        for (int jj = 0; jj < 4; ++jj) {
            v4f t = 1.0f - a[jj] * a[jj];
            chv[0][jj] = a[jj];
            chv[1][jj] = t * wx[jj];
            chv[2][jj] = t * wy[jj];
            chv[3][jj] = (a[jj] * t) * n2[jj];  // z_lap = 0 at layer 0
        }
        #pragma unroll
        for (int pp = 0; pp < 4; ++pp)
            #pragma unroll
            for (int c = 0; c < 4; ++c) {
                const int row = (c * 32 + p0 + pp) * KP + j0;
                uint2 h = { pk2(chv[c][0][pp], chv[c][1][pp]),
                            pk2(chv[c][2][pp], chv[c][3][pp]) };
                *(uint2*)&sBh[row] = h;
            }
    }
    __syncthreads();

    v4f acc[4][4];   // [mt][c]
    auto gemm = [&](const unsigned short* wsh, const unsigned short* wsl) {
        #pragma unroll
        for (int mt = 0; mt < 4; ++mt)
            #pragma unroll
            for (int c = 0; c < 4; ++c)
                acc[mt][c] = (v4f){0.0f, 0.0f, 0.0f, 0.0f};
        #pragma unroll
        for (int ks = 0; ks < 4; ++ks) {
            const int cur = ks & 1, nxt = cur ^ 1;
            if (ks < 3) {   // prefetch next stage from L2 while MFMAs run
                #pragma unroll
                for (int mt = 0; mt < 4; ++mt) {
                    const int idx = (mh * 4 + mt) * 256 + (ks + 1) * 64 + lane;
                    whi[nxt][mt] = *(const s8v*)&wsh[(size_t)idx * 8];
                    wlo[nxt][mt] = *(const s8v*)&wsl[(size_t)idx * 8];
                }
            }
            #pragma unroll
            for (int c = 0; c < 4; ++c) {
                const int rb = ((c * 2 + pt) * 16 + l15) * KP + quad * 8 + ks * 32;
                s8v bh = *(const s8v*)&sBh[rb];
                #pragma unroll
                for (int mt = 0; mt < 4; ++mt)
                    acc[mt][c] = __builtin_amdgcn_mfma_f32_16x16x32_bf16(
                        whi[cur][mt], bh, acc[mt][c], 0, 0, 0);
                #pragma unroll
                for (int mt = 0; mt < 4; ++mt)
                    acc[mt][c] = __builtin_amdgcn_mfma_f32_16x16x32_bf16(
                        wlo[cur][mt], bh, acc[mt][c], 0, 0, 0);
            }
        }
    };

    // ---- hidden layer 1 ----
    gemm(ws1h, ws1l);
    __syncthreads();            // all waves done reading sB

    // W2 stage-0 prefetch BEFORE the tanh chain: latency hides under epilogue
    #pragma unroll
    for (int mt = 0; mt < 4; ++mt) {
        const int idx = (mh * 4 + mt) * 256 + lane;
        whi[0][mt] = *(const s8v*)&ws2h[(size_t)idx * 8];
        wlo[0][mt] = *(const s8v*)&ws2l[(size_t)idx * 8];
    }

    {   // epilogue L0: all 4 channels -> sB
        v4f z[4], a[4];
        #pragma unroll
        for (int mt = 0; mt < 4; ++mt) {
            const int jb = (mh * 4 + mt) * 16 + quad * 4;
            z[mt] = acc[mt][0] + *(const v4f*)&b1[jb];
        }
        tanh16(z, a);
        #pragma unroll
        for (int mt = 0; mt < 4; ++mt) {
            const int jb = (mh * 4 + mt) * 16 + quad * 4;
            const int rowb = (pt * 16 + l15) * KP + jb;
            v4f t  = 1.0f - a[mt] * a[mt];
            v4f zx = acc[mt][1], zy = acc[mt][2], zl = acc[mt][3];
            v4f s2 = zx * zx + zy * zy;
            v4f u  = (-2.0f * a[mt]) * s2 + zl;
            v4f c1 = t * zx;
            v4f c2 = t * zy;
            v4f c3 = t * u;
            uint2 h0 = { pk2(a[mt][0], a[mt][1]), pk2(a[mt][2], a[mt][3]) };
            uint2 h1 = { pk2(c1[0], c1[1]), pk2(c1[2], c1[3]) };
            uint2 h2 = { pk2(c2[0], c2[1]), pk2(c2[2], c2[3]) };
            uint2 h3 = { pk2(c3[0], c3[1]), pk2(c3[2], c3[3]) };
            *(uint2*)&sBh[rowb]               = h0;
            *(uint2*)&sBh[rowb + 32 * KP]     = h1;
            *(uint2*)&sBh[rowb + 2 * 32 * KP] = h2;
            *(uint2*)&sBh[rowb + 3 * 32 * KP] = h3;
        }
    }
    __syncthreads();

    // ---- hidden layer 2 + fused readout (no sB writes, no extra barriers) ----
    gemm(ws2h, ws2l);

    {
        v4f z[4], a[4];
        #pragma unroll
        for (int mt = 0; mt < 4; ++mt) {
            const int jb = (mh * 4 + mt) * 16 + quad * 4;
            z[mt] = acc[mt][0] + *(const v4f*)&b2[jb];
        }
        tanh16(z, a);
        float part = 0.0f;
        if (is_bd) {            // boundary: pred = a . W3
            #pragma unroll
            for (int mt = 0; mt < 4; ++mt) {
                v4f pr = a[mt] * w3v[mt];
                part += (pr[0] + pr[1]) + (pr[2] + pr[3]);
            }
        } else {                // interior: pred = lap . W3
            #pragma unroll
            for (int mt = 0; mt < 4; ++mt) {
                v4f t  = 1.0f - a[mt] * a[mt];
                v4f zx = acc[mt][1], zy = acc[mt][2], zl = acc[mt][3];
                v4f s2 = zx * zx + zy * zy;
                v4f u  = (-2.0f * a[mt]) * s2 + zl;
                v4f pr = (t * u) * w3v[mt];
                part += (pr[0] + pr[1]) + (pr[2] + pr[3]);
            }
        }
        // sum over this wave's 32 j-rows: reduce across the 4 quads (same point p)
        part += __shfl_xor(part, 16, 64);
        part += __shfl_xor(part, 32, 64);
        // exchange across the two mh halves through 128B of LDS
        if (mh == 1 && quad == 0) sPart[pt * 16 + l15] = part;
        __syncthreads();
        if (mh == 0) {
            const int p = pt * 16 + l15;
            float pred = part + sPart[p] + (is_bd ? b3[0] : 0.0f);
            float d = pred - tgt[pbase + p];
            float sq = (quad == 0) ? d * d : 0.0f;
            sq += __shfl_xor(sq, 1, 64);
            sq += __shfl_xor(sq, 2, 64);
            sq += __shfl_xor(sq, 4, 64);
            sq += __shfl_xor(sq, 8, 64);
            sq += __shfl_xor(sq, 16, 64);
            sq += __shfl_xor(sq, 32, 64);
            if (lane == 0)
                atomicAdd(out + (is_bd ? 0 : 1),
                          sq * (is_bd ? scale_bd : scale_int));
        }
    }
}

extern "C" void kernel_launch(void* const* d_in, const int* in_sizes, int n_in,
                              void* d_out, int out_size, void* d_ws, size_t ws_size,
                              hipStream_t stream) {
    const float* xy_int = (const float*)d_in[0];
    const float* f      = (const float*)d_in[1];
    const float* xy_bd  = (const float*)d_in[2];
    const float* g      = (const float*)d_in[3];
    const float* W0 = (const float*)d_in[4];
    const float* b0 = (const float*)d_in[5];
    const float* W1 = (const float*)d_in[6];
    const float* b1 = (const float*)d_in[7];
    const float* W2 = (const float*)d_in[8];
    const float* b2 = (const float*)d_in[9];
    const float* W3 = (const float*)d_in[10];
    const float* b3 = (const float*)d_in[11];
    float* out = (float*)d_out;
    unsigned short* ws = (unsigned short*)d_ws;   // needs 256 KB

    const int n_int = in_sizes[0] / 2;   // 262144
    const int n_bd  = in_sizes[2] / 2;   // 16384

    prep_w_kernel<<<16, 256, 0, stream>>>(W1, W2, ws, out);

    const int smem = (4 * 32 * KP) * 2 + PTS * 4;  // 34,944 B -> 4 blocks/CU
    const int gi = n_int / PTS;
    const int gb = n_bd / PTS;

    pinn_mfma_kernel<<<gi + gb, 256, smem, stream>>>(
        xy_int, f, xy_bd, g, W0, b0, b1, b2, W3, b3, ws, out,
        gi, 0.5f / (float)n_int, 0.5f / (float)n_bd);
}

// Round 10
// 325.172 us; speedup vs baseline: 1.0128x; 1.0128x over previous
//
#include <hip/hip_runtime.h>

#define HID 128
#define PTS 32
#define KP  136   // sB k-row stride in bf16 units (128 + 8 pad)
#define FRAGS_PER_W 2048           // 8 mtg * 4 ks * 64 lanes
#define WS_ELEMS (FRAGS_PER_W * 8) // ushorts per (w, hi/lo) plane

typedef float v4f __attribute__((ext_vector_type(4)));
typedef short s8v __attribute__((ext_vector_type(8)));          // 8 bf16 (MFMA A/B frag)

__device__ __forceinline__ unsigned short f2bf(float f) {       // RNE (prep only)
    unsigned u = __builtin_bit_cast(unsigned, f);
    u = (u + 0x7FFFu + ((u >> 16) & 1u)) >> 16;
    return (unsigned short)u;
}
__device__ __forceinline__ float bf2f(unsigned short h) {
    unsigned u = ((unsigned)h) << 16;
    return __builtin_bit_cast(float, u);
}

// --- packed fp32 -> 2x bf16 (RNE), 1 instr on gfx950 ---
#if __has_builtin(__builtin_amdgcn_cvt_pk_bf16_f32)
typedef __bf16 bf16x2 __attribute__((ext_vector_type(2)));
__device__ __forceinline__ unsigned pk2(float f0, float f1) {   // (bf(f1)<<16)|bf(f0)
    return __builtin_bit_cast(unsigned, __builtin_amdgcn_cvt_pk_bf16_f32(f0, f1));
}
#else
__device__ __forceinline__ unsigned pk2(float f0, float f1) {
    unsigned u0 = __builtin_bit_cast(unsigned, f0);
    unsigned u1 = __builtin_bit_cast(unsigned, f1);
    u0 += 0x7FFFu + ((u0 >> 16) & 1u);
    u1 += 0x7FFFu + ((u1 >> 16) & 1u);
    return __builtin_amdgcn_perm(u1, u0, 0x07060302u);
}
#endif

__device__ __forceinline__ float expf2x(float x) {              // exp(2x) via v_exp
#if __has_builtin(__builtin_amdgcn_exp2f)
    return __builtin_amdgcn_exp2f(x * 2.885390081777927f);      // 2*log2(e)
#else
    return __expf(2.0f * x);
#endif
}

// 8-wide staged tanh: 8 independent exp chains, then 8 rcps. Enough ILP to
// cover the quarter-rate trans pipe without round-9's 32-temp live set
// (which blew the (256,4) register budget and spilled 279 MB to scratch).
__device__ __forceinline__ void tanh8(v4f z0, v4f z1, v4f& a0, v4f& a1) {
    v4f e0, e1;
    #pragma unroll
    for (int i = 0; i < 4; ++i) e0[i] = expf2x(z0[i]);
    #pragma unroll
    for (int i = 0; i < 4; ++i) e1[i] = expf2x(z1[i]);
    v4f d0 = e0 + 1.0f, d1 = e1 + 1.0f;
    v4f r0, r1;
    #pragma unroll
    for (int i = 0; i < 4; ++i) r0[i] = __builtin_amdgcn_rcpf(d0[i]);
    #pragma unroll
    for (int i = 0; i < 4; ++i) r1[i] = __builtin_amdgcn_rcpf(d1[i]);
    a0 = 1.0f - 2.0f * r0;
    a1 = 1.0f - 2.0f * r1;
}

// One-time: W1/W2 -> RNE-split bf16 A-fragments, frag-linear in d_ws; zero d_out.
// ws plane order: [W1hi][W1lo][W2hi][W2lo]; frag idx r = mtg*256 + ks*64 + lane.
__global__ __launch_bounds__(256) void prep_w_kernel(
    const float* __restrict__ W1, const float* __restrict__ W2,
    unsigned short* __restrict__ ws, float* __restrict__ out)
{
    if (blockIdx.x == 0 && threadIdx.x < 2) out[threadIdx.x] = 0.0f;
    const int t = blockIdx.x * 256 + threadIdx.x;   // 0..4095
    const int w = t >> 11;
    const int r = t & 2047;
    const int mtg = r >> 8;
    const int ks = (r >> 6) & 3;
    const int lane = r & 63;
    const int m = mtg * 16 + (lane & 15);
    const int kb = ks * 32 + (lane >> 4) * 8;
    const float* W = w ? W2 : W1;
    s8v hv, lv;
    #pragma unroll
    for (int i = 0; i < 8; ++i) {
        float f = W[(kb + i) * HID + m];            // A[m][k] = W[k][m]
        unsigned short hh = f2bf(f);
        hv[i] = (short)hh;
        lv[i] = (short)f2bf(f - bf2f(hh));
    }
    *(s8v*)&ws[((size_t)(w * 2 + 0) * FRAGS_PER_W + r) * 8] = hv;
    *(s8v*)&ws[((size_t)(w * 2 + 1) * FRAGS_PER_W + r) * 8] = lv;
}

// Fused interior+boundary. Blocks [0,gi): interior (lap readout); rest: boundary.
// One block = 32 points, 4 channels (0=val,1=dx,2=dy,3=lap).
// 2-product split-bf16 MFMA (W = whi+wlo exact to 2^-18, register-resident),
// activations single RNE bf16 in LDS. Readout fused into the L1 epilogue
// (register dot with W3 + shuffles + 128B LDS mh-exchange). 4 barriers total.
// W stage-0 prefetches hoisted across barriers. NO lambda (SROA), NO w3v
// preload, tanh8 pairs: peak regs ~ round-8 level -> no scratch.
// Wave grid: (j-half mh) x (p-half pt). C/D layout (m89): col=lane&15, row=quad*4+reg.
__global__ __launch_bounds__(256, 4) void pinn_mfma_kernel(
    const float* __restrict__ xy_int, const float* __restrict__ f_t,
    const float* __restrict__ xy_bd, const float* __restrict__ g_t,
    const float* __restrict__ W0, const float* __restrict__ b0,
    const float* __restrict__ b1, const float* __restrict__ b2,
    const float* __restrict__ W3, const float* __restrict__ b3,
    const unsigned short* __restrict__ ws, float* __restrict__ out,
    int gi, float scale_int, float scale_bd)
{
    extern __shared__ char smem_raw[];
    unsigned short* sBh = (unsigned short*)smem_raw;     // [4*32][KP] bf16 (RNE)
    float* sPart = (float*)(sBh + 4 * 32 * KP);          // [PTS] cross-mh partials

    const bool is_bd = (int)blockIdx.x >= gi;
    const float* __restrict__ xy  = is_bd ? xy_bd : xy_int;
    const float* __restrict__ tgt = is_bd ? g_t : f_t;
    const int pbase = (is_bd ? ((int)blockIdx.x - gi) : (int)blockIdx.x) * PTS;

    const int tid   = threadIdx.x;
    const int lane  = tid & 63;
    const int l15   = lane & 15;
    const int quad  = lane >> 4;
    const int mh    = (tid >> 6) & 1;   // j-half: m-tiles mh*4..mh*4+3
    const int pt    = tid >> 7;         // p-half: cols pt*16..pt*16+15

    // ---- W1 stage-0 prefetch FIRST: L2 latency hides under layer-0 math ----
    s8v whi[2][4], wlo[2][4];       // [buf][mt], double-buffered per ks stage
    #pragma unroll
    for (int mt = 0; mt < 4; ++mt) {
        const int idx = (mh * 4 + mt) * 256 + lane;       // ks = 0
        whi[0][mt] = *(const s8v*)&ws[(size_t)idx * 8];
        wlo[0][mt] = *(const s8v*)&ws[(size_t)(WS_ELEMS + (size_t)idx * 8)];
    }

    // ---- layer 0: 2 -> 128, staged-ILP VALU, RNE-bf16 store into sB ----
    {
        const int tj = tid & 31, tp = tid >> 5;
        const int j0 = tj * 4, p0 = tp * 4;
        v4f xv, yv;
        #pragma unroll
        for (int pp = 0; pp < 4; ++pp) {
            const float2 t2 = ((const float2*)xy)[pbase + p0 + pp];
            xv[pp] = t2.x; yv[pp] = t2.y;
        }
        float wx[4], wy[4], bb[4], n2[4];
        #pragma unroll
        for (int jj = 0; jj < 4; ++jj) {
            wx[jj] = W0[j0 + jj];
            wy[jj] = W0[HID + j0 + jj];
            bb[jj] = b0[j0 + jj];
            n2[jj] = -2.0f * fmaf(wx[jj], wx[jj], wy[jj] * wy[jj]);
        }
        v4f chv[4][4];                          // [c][jj], vector over pp
        #pragma unroll
        for (int jp = 0; jp < 2; ++jp) {        // jj pairs
            const int ja = jp * 2, jb2 = jp * 2 + 1;
            v4f z0 = xv * wx[ja]  + yv * wy[ja]  + bb[ja];
            v4f z1 = xv * wx[jb2] + yv * wy[jb2] + bb[jb2];
            v4f a0, a1;
            tanh8(z0, z1, a0, a1);
            v4f t0 = 1.0f - a0 * a0, t1 = 1.0f - a1 * a1;
            chv[0][ja] = a0;            chv[0][jb2] = a1;
            chv[1][ja] = t0 * wx[ja];   chv[1][jb2] = t1 * wx[jb2];
            chv[2][ja] = t0 * wy[ja];   chv[2][jb2] = t1 * wy[jb2];
            chv[3][ja] = (a0 * t0) * n2[ja];
            chv[3][jb2] = (a1 * t1) * n2[jb2];
        }
        #pragma unroll
        for (int pp = 0; pp < 4; ++pp)
            #pragma unroll
            for (int c = 0; c < 4; ++c) {
                const int row = (c * 32 + p0 + pp) * KP + j0;
                uint2 h = { pk2(chv[c][0][pp], chv[c][1][pp]),
                            pk2(chv[c][2][pp], chv[c][3][pp]) };
                *(uint2*)&sBh[row] = h;
            }
    }
    __syncthreads();

    v4f acc[4][4];   // [mt][c]

    #pragma unroll
    for (int L = 0; L < 2; ++L) {
        const unsigned short* wsh = ws + (size_t)(2 * L) * WS_ELEMS;
        const unsigned short* wsl = ws + (size_t)(2 * L + 1) * WS_ELEMS;

        #pragma unroll
        for (int mt = 0; mt < 4; ++mt)
            #pragma unroll
            for (int c = 0; c < 4; ++c)
                acc[mt][c] = (v4f){0.0f, 0.0f, 0.0f, 0.0f};

        #pragma unroll
        for (int ks = 0; ks < 4; ++ks) {
            const int cur = ks & 1, nxt = cur ^ 1;
            if (ks < 3) {   // prefetch next stage from L2 while MFMAs run
                #pragma unroll
                for (int mt = 0; mt < 4; ++mt) {
                    const int idx = (mh * 4 + mt) * 256 + (ks + 1) * 64 + lane;
                    whi[nxt][mt] = *(const s8v*)&wsh[(size_t)idx * 8];
                    wlo[nxt][mt] = *(const s8v*)&wsl[(size_t)idx * 8];
                }
            }
            #pragma unroll
            for (int c = 0; c < 4; ++c) {
                const int rb = ((c * 2 + pt) * 16 + l15) * KP + quad * 8 + ks * 32;
                s8v bh = *(const s8v*)&sBh[rb];
                #pragma unroll
                for (int mt = 0; mt < 4; ++mt)
                    acc[mt][c] = __builtin_amdgcn_mfma_f32_16x16x32_bf16(
                        whi[cur][mt], bh, acc[mt][c], 0, 0, 0);
                #pragma unroll
                for (int mt = 0; mt < 4; ++mt)
                    acc[mt][c] = __builtin_amdgcn_mfma_f32_16x16x32_bf16(
                        wlo[cur][mt], bh, acc[mt][c], 0, 0, 0);
            }
        }

        if (L == 0) {
            __syncthreads();        // all waves done reading sB

            // W2 stage-0 prefetch BEFORE the tanh chain: hides under epilogue
            #pragma unroll
            for (int mt = 0; mt < 4; ++mt) {
                const int idx = (mh * 4 + mt) * 256 + lane;
                whi[0][mt] = *(const s8v*)&ws[(size_t)(2 * WS_ELEMS) + (size_t)idx * 8];
                wlo[0][mt] = *(const s8v*)&ws[(size_t)(3 * WS_ELEMS) + (size_t)idx * 8];
            }

            // epilogue L0: all 4 channels -> sB, mt pairs
            #pragma unroll
            for (int mp = 0; mp < 2; ++mp) {
                const int m0 = mp * 2, m1 = mp * 2 + 1;
                const int jb0 = (mh * 4 + m0) * 16 + quad * 4;
                const int jb1 = (mh * 4 + m1) * 16 + quad * 4;
                v4f z0 = acc[m0][0] + *(const v4f*)&b1[jb0];
                v4f z1 = acc[m1][0] + *(const v4f*)&b1[jb1];
                v4f a0, a1;
                tanh8(z0, z1, a0, a1);
                #pragma unroll
                for (int h = 0; h < 2; ++h) {
                    const int mt = mp * 2 + h;
                    const v4f a = h ? a1 : a0;
                    const int jb = h ? jb1 : jb0;
                    const int rowb = (pt * 16 + l15) * KP + jb;
                    v4f t  = 1.0f - a * a;
                    v4f zx = acc[mt][1], zy = acc[mt][2], zl = acc[mt][3];
                    v4f s2 = zx * zx + zy * zy;
                    v4f u  = (-2.0f * a) * s2 + zl;
                    v4f c1 = t * zx;
                    v4f c2 = t * zy;
                    v4f c3 = t * u;
                    uint2 h0 = { pk2(a[0], a[1]),  pk2(a[2], a[3])  };
                    uint2 h1 = { pk2(c1[0], c1[1]), pk2(c1[2], c1[3]) };
                    uint2 h2 = { pk2(c2[0], c2[1]), pk2(c2[2], c2[3]) };
                    uint2 h3 = { pk2(c3[0], c3[1]), pk2(c3[2], c3[3]) };
                    *(uint2*)&sBh[rowb]               = h0;
                    *(uint2*)&sBh[rowb + 32 * KP]     = h1;
                    *(uint2*)&sBh[rowb + 2 * 32 * KP] = h2;
                    *(uint2*)&sBh[rowb + 3 * 32 * KP] = h3;
                }
            }
            __syncthreads();
        }
    }

    // ---- fused readout on L1 acc (registers only; W3 from L2) ----
    {
        float part = 0.0f;
        #pragma unroll
        for (int mp = 0; mp < 2; ++mp) {
            const int m0 = mp * 2, m1 = mp * 2 + 1;
            const int jb0 = (mh * 4 + m0) * 16 + quad * 4;
            const int jb1 = (mh * 4 + m1) * 16 + quad * 4;
            v4f z0 = acc[m0][0] + *(const v4f*)&b2[jb0];
            v4f z1 = acc[m1][0] + *(const v4f*)&b2[jb1];
            v4f a0, a1;
            tanh8(z0, z1, a0, a1);
            #pragma unroll
            for (int h = 0; h < 2; ++h) {
                const int mt = mp * 2 + h;
                const v4f a = h ? a1 : a0;
                const v4f w3 = *(const v4f*)&W3[(mh * 4 + mt) * 16 + quad * 4];
                v4f pr;
                if (is_bd) {
                    pr = a * w3;                        // pred = a . W3
                } else {
                    v4f t  = 1.0f - a * a;
                    v4f zx = acc[mt][1], zy = acc[mt][2], zl = acc[mt][3];
                    v4f s2 = zx * zx + zy * zy;
                    v4f u  = (-2.0f * a) * s2 + zl;
                    pr = (t * u) * w3;                  // pred = lap . W3
                }
                part += (pr[0] + pr[1]) + (pr[2] + pr[3]);
            }
        }
        // sum over this wave's 32 j-rows: reduce across the 4 quads (same point)
        part += __shfl_xor(part, 16, 64);
        part += __shfl_xor(part, 32, 64);
        // exchange across the two mh halves through 128B of LDS
        if (mh == 1 && quad == 0) sPart[pt * 16 + l15] = part;
        __syncthreads();
        if (mh == 0) {
            const int p = pt * 16 + l15;
            float pred = part + sPart[p] + (is_bd ? b3[0] : 0.0f);
            float d = pred - tgt[pbase + p];
            float sq = (quad == 0) ? d * d : 0.0f;
            sq += __shfl_xor(sq, 1, 64);
            sq += __shfl_xor(sq, 2, 64);
            sq += __shfl_xor(sq, 4, 64);
            sq += __shfl_xor(sq, 8, 64);
            sq += __shfl_xor(sq, 16, 64);
            sq += __shfl_xor(sq, 32, 64);
            if (lane == 0)
                atomicAdd(out + (is_bd ? 0 : 1),
                          sq * (is_bd ? scale_bd : scale_int));
        }
    }
}

extern "C" void kernel_launch(void* const* d_in, const int* in_sizes, int n_in,
                              void* d_out, int out_size, void* d_ws, size_t ws_size,
                              hipStream_t stream) {
    const float* xy_int = (const float*)d_in[0];
    const float* f      = (const float*)d_in[1];
    const float* xy_bd  = (const float*)d_in[2];
    const float* g      = (const float*)d_in[3];
    const float* W0 = (const float*)d_in[4];
    const float* b0 = (const float*)d_in[5];
    const float* W1 = (const float*)d_in[6];
    const float* b1 = (const float*)d_in[7];
    const float* W2 = (const float*)d_in[8];
    const float* b2 = (const float*)d_in[9];
    const float* W3 = (const float*)d_in[10];
    const float* b3 = (const float*)d_in[11];
    float* out = (float*)d_out;
    unsigned short* ws = (unsigned short*)d_ws;   // needs 256 KB

    const int n_int = in_sizes[0] / 2;   // 262144
    const int n_bd  = in_sizes[2] / 2;   // 16384

    prep_w_kernel<<<16, 256, 0, stream>>>(W1, W2, ws, out);

    const int smem = (4 * 32 * KP) * 2 + PTS * 4;  // 34,944 B -> 4 blocks/CU
    const int gi = n_int / PTS;
    const int gb = n_bd / PTS;

    pinn_mfma_kernel<<<gi + gb, 256, smem, stream>>>(
        xy_int, f, xy_bd, g, W0, b0, b1, b2, W3, b3, ws, out,
        gi, 0.5f / (float)n_int, 0.5f / (float)n_bd);
}

// Round 11
// 228.368 us; speedup vs baseline: 1.4421x; 1.4239x over previous
//
#include <hip/hip_runtime.h>

#define HID 128
#define PTS 32
#define KP  136   // sB k-row stride in bf16 units (128 + 8 pad)
#define FRAGS_PER_W 2048           // 8 mtg * 4 ks * 64 lanes
#define WS_ELEMS (FRAGS_PER_W * 8) // ushorts per (w, hi/lo) plane

typedef float v4f __attribute__((ext_vector_type(4)));
typedef short s8v __attribute__((ext_vector_type(8)));          // 8 bf16 (MFMA A/B frag)

__device__ __forceinline__ unsigned short f2bf(float f) {       // RNE (prep only)
    unsigned u = __builtin_bit_cast(unsigned, f);
    u = (u + 0x7FFFu + ((u >> 16) & 1u)) >> 16;
    return (unsigned short)u;
}
__device__ __forceinline__ float bf2f(unsigned short h) {
    unsigned u = ((unsigned)h) << 16;
    return __builtin_bit_cast(float, u);
}

// --- packed fp32 -> 2x bf16 (RNE), 1 instr on gfx950 ---
#if __has_builtin(__builtin_amdgcn_cvt_pk_bf16_f32)
typedef __bf16 bf16x2 __attribute__((ext_vector_type(2)));
__device__ __forceinline__ unsigned pk2(float f0, float f1) {   // (bf(f1)<<16)|bf(f0)
    return __builtin_bit_cast(unsigned, __builtin_amdgcn_cvt_pk_bf16_f32(f0, f1));
}
#else
__device__ __forceinline__ unsigned pk2(float f0, float f1) {
    unsigned u0 = __builtin_bit_cast(unsigned, f0);
    unsigned u1 = __builtin_bit_cast(unsigned, f1);
    u0 += 0x7FFFu + ((u0 >> 16) & 1u);
    u1 += 0x7FFFu + ((u1 >> 16) & 1u);
    return __builtin_amdgcn_perm(u1, u0, 0x07060302u);
}
#endif
// 4 fp32 -> packed RNE bf16 x4
__device__ __forceinline__ uint2 pk4(const float* f) {
    uint2 h;
    h.x = pk2(f[0], f[1]);
    h.y = pk2(f[2], f[3]);
    return h;
}

// tanh(x) = 1 - 2/(exp(2x)+1); single mul + v_exp + v_rcp
__device__ __forceinline__ float fast_tanh(float x) {
#if __has_builtin(__builtin_amdgcn_exp2f)
    float e = __builtin_amdgcn_exp2f(x * 2.885390081777927f);   // 2*log2(e)
#else
    float e = __expf(2.0f * x);
#endif
    float r = __builtin_amdgcn_rcpf(e + 1.0f);
    return 1.0f - 2.0f * r;
}

// One-time: W1/W2 -> RNE-split bf16 A-fragments, frag-linear in d_ws; zero d_out.
// ws plane order: [W1hi][W1lo][W2hi][W2lo]; frag idx r = mtg*256 + ks*64 + lane.
__global__ __launch_bounds__(256) void prep_w_kernel(
    const float* __restrict__ W1, const float* __restrict__ W2,
    unsigned short* __restrict__ ws, float* __restrict__ out)
{
    if (blockIdx.x == 0 && threadIdx.x < 2) out[threadIdx.x] = 0.0f;
    const int t = blockIdx.x * 256 + threadIdx.x;   // 0..4095
    const int w = t >> 11;
    const int r = t & 2047;
    const int mtg = r >> 8;
    const int ks = (r >> 6) & 3;
    const int lane = r & 63;
    const int m = mtg * 16 + (lane & 15);
    const int kb = ks * 32 + (lane >> 4) * 8;
    const float* W = w ? W2 : W1;
    s8v hv, lv;
    #pragma unroll
    for (int i = 0; i < 8; ++i) {
        float f = W[(kb + i) * HID + m];            // A[m][k] = W[k][m]
        unsigned short hh = f2bf(f);
        hv[i] = (short)hh;
        lv[i] = (short)f2bf(f - bf2f(hh));
    }
    *(s8v*)&ws[((size_t)(w * 2 + 0) * FRAGS_PER_W + r) * 8] = hv;
    *(s8v*)&ws[((size_t)(w * 2 + 1) * FRAGS_PER_W + r) * 8] = lv;
}

// Round-7 structure EXACTLY (163 us proven: MfmaUtil+VALUBusy = 103% pipe-sum).
// Only change: HW v_cvt_pk_bf16_f32 packing + 1-mul exp2 tanh (pure VALU deletion).
// Rounds 8-10 (vectorized chains / hoisted prefetch / fused readout) all REGRESSED
// under the (256,4) register budget -- do not reintroduce.
// Fused interior+boundary. Blocks [0,gi): interior (readout=lap ch 3, no b3);
// blocks [gi, gi+gb): boundary (readout=value ch 0, +b3). All branches block-uniform.
// One block = 32 points, 4 channels (0=val,1=dx,2=dy,3=lap).
// 2-product split-bf16 MFMA: W = whi + wlo (exact to 2^-18, registers),
// activations single RNE bf16 in LDS. Wave grid: (j-half mh) x (p-half pt).
// C/D layout (m89): col=lane&15, row=quad*4+reg. LDS 34.9 KB -> 4 blocks/CU.
__global__ __launch_bounds__(256, 4) void pinn_mfma_kernel(
    const float* __restrict__ xy_int, const float* __restrict__ f_t,
    const float* __restrict__ xy_bd, const float* __restrict__ g_t,
    const float* __restrict__ W0, const float* __restrict__ b0,
    const float* __restrict__ b1, const float* __restrict__ b2,
    const float* __restrict__ W3, const float* __restrict__ b3,
    const unsigned short* __restrict__ ws, float* __restrict__ out,
    int gi, float scale_int, float scale_bd)
{
    extern __shared__ char smem_raw[];
    unsigned short* sBh = (unsigned short*)smem_raw;     // [4*32][KP] bf16 (RNE)
    float* sRed = (float*)(sBh + 4 * 32 * KP);           // [PTS]

    const bool is_bd = (int)blockIdx.x >= gi;
    const float* __restrict__ xy  = is_bd ? xy_bd : xy_int;
    const float* __restrict__ tgt = is_bd ? g_t : f_t;
    const int rc = is_bd ? 0 : 3;                        // readout channel
    const int pbase = (is_bd ? ((int)blockIdx.x - gi) : (int)blockIdx.x) * PTS;

    const int tid   = threadIdx.x;
    const int lane  = tid & 63;
    const int wave  = tid >> 6;
    const int l15   = lane & 15;
    const int quad  = lane >> 4;
    const int mh    = wave & 1;     // j-half: m-tiles mh*4..mh*4+3
    const int pt    = wave >> 1;    // p-half: cols pt*16..pt*16+15

    // ---- layer 0: 2 -> 128, VALU, RNE-bf16 store into sB ----
    {
        const int tj = tid & 31, tp = tid >> 5;
        const int j0 = tj * 4, p0 = tp * 4;
        float wx[4], wy[4], bb[4];
        #pragma unroll
        for (int jj = 0; jj < 4; ++jj) {
            wx[jj] = W0[j0 + jj];
            wy[jj] = W0[HID + j0 + jj];
            bb[jj] = b0[j0 + jj];
        }
        #pragma unroll
        for (int pp = 0; pp < 4; ++pp) {
            const int p = p0 + pp;
            const float2 t2 = ((const float2*)xy)[pbase + p];
            float chv[4][4];                    // [c][jj]
            #pragma unroll
            for (int jj = 0; jj < 4; ++jj) {
                float z = fmaf(t2.x, wx[jj], fmaf(t2.y, wy[jj], bb[jj]));
                float a = fast_tanh(z);
                float t = fmaf(-a, a, 1.0f);
                float s2 = fmaf(wx[jj], wx[jj], wy[jj] * wy[jj]);
                chv[0][jj] = a;
                chv[1][jj] = t * wx[jj];
                chv[2][jj] = t * wy[jj];
                chv[3][jj] = -2.0f * a * t * s2;        // z_lap = 0 at layer 0
            }
            #pragma unroll
            for (int c = 0; c < 4; ++c) {
                const int row = (c * 32 + p) * KP + j0; // j0 mult of 4 -> 8B aligned
                *(uint2*)&sBh[row] = pk4(chv[c]);
            }
        }
    }
    __syncthreads();

    // ---- hidden layers: D = (Whi + Wlo)(A-op) x Act(B-op), 2-product ----
    #pragma unroll
    for (int L = 0; L < 2; ++L) {
        const unsigned short* wshi = ws + (size_t)L * 2 * WS_ELEMS;
        const unsigned short* wslo = wshi + WS_ELEMS;

        s8v whi[2][4], wlo[2][4];   // [buf][mt] double-buffered per ks stage
        #pragma unroll
        for (int mt = 0; mt < 4; ++mt) {
            const int idx = (mh * 4 + mt) * 256 + lane;   // ks = 0
            whi[0][mt] = *(const s8v*)&wshi[(size_t)idx * 8];
            wlo[0][mt] = *(const s8v*)&wslo[(size_t)idx * 8];
        }

        v4f acc[4][4];   // [mt][c]
        #pragma unroll
        for (int mt = 0; mt < 4; ++mt)
            #pragma unroll
            for (int c = 0; c < 4; ++c)
                acc[mt][c] = (v4f){0.0f, 0.0f, 0.0f, 0.0f};

        #pragma unroll
        for (int ks = 0; ks < 4; ++ks) {
            const int cur = ks & 1, nxt = cur ^ 1;
            if (ks < 3) {   // prefetch next stage from L2 while MFMAs run
                #pragma unroll
                for (int mt = 0; mt < 4; ++mt) {
                    const int idx = (mh * 4 + mt) * 256 + (ks + 1) * 64 + lane;
                    whi[nxt][mt] = *(const s8v*)&wshi[(size_t)idx * 8];
                    wlo[nxt][mt] = *(const s8v*)&wslo[(size_t)idx * 8];
                }
            }
            #pragma unroll
            for (int c = 0; c < 4; ++c) {
                const int rb = ((c * 2 + pt) * 16 + l15) * KP + quad * 8 + ks * 32;
                s8v bh = *(const s8v*)&sBh[rb];
                #pragma unroll
                for (int mt = 0; mt < 4; ++mt)
                    acc[mt][c] = __builtin_amdgcn_mfma_f32_16x16x32_bf16(
                        whi[cur][mt], bh, acc[mt][c], 0, 0, 0);
                #pragma unroll
                for (int mt = 0; mt < 4; ++mt)
                    acc[mt][c] = __builtin_amdgcn_mfma_f32_16x16x32_bf16(
                        wlo[cur][mt], bh, acc[mt][c], 0, 0, 0);
            }
        }
        __syncthreads();            // all waves done reading sB

        const float* __restrict__ bptr = (L == 0) ? b1 : b2;
        #pragma unroll
        for (int mt = 0; mt < 4; ++mt) {
            const int jb = (mh * 4 + mt) * 16 + quad * 4;   // 4 consecutive j
            float chv[4][4];                                // [c][r]
            #pragma unroll
            for (int r = 0; r < 4; ++r) {
                float z = acc[mt][0][r] + bptr[jb + r];
                float a = fast_tanh(z);
                float t = fmaf(-a, a, 1.0f);
                float zx = acc[mt][1][r], zy = acc[mt][2][r], zl = acc[mt][3][r];
                float s2 = fmaf(zx, zx, zy * zy);
                chv[0][r] = a;
                chv[1][r] = t * zx;
                chv[2][r] = t * zy;
                chv[3][r] = fmaf(t, zl, -2.0f * a * t * s2);
            }
            #pragma unroll
            for (int c = 0; c < 4; ++c) {
                if (L == 1 && c != rc) continue;    // uniform: skip dead conv+store
                const int row = (c * 32 + pt * 16 + l15) * KP + jb;
                *(uint2*)&sBh[row] = pk4(chv[c]);
            }
        }
        __syncthreads();
    }

    // ---- readout: dot with W3 over k, 8 lanes per point ----
    {
        const int p  = tid >> 3;
        const int i  = tid & 7;
        const int k0 = i * 16;
        const int row = (rc * 32 + p) * KP + k0;
        float r = 0.0f;
        #pragma unroll
        for (int h = 0; h < 2; ++h) {
            s8v vh = *(const s8v*)&sBh[row + h * 8];
            #pragma unroll
            for (int t = 0; t < 8; ++t)
                r = fmaf(bf2f((unsigned short)vh[t]), W3[k0 + h * 8 + t], r);
        }
        r += __shfl_xor(r, 1, 64);
        r += __shfl_xor(r, 2, 64);
        r += __shfl_xor(r, 4, 64);
        if (i == 0) {
            float d = r + (is_bd ? b3[0] : 0.0f) - tgt[pbase + p];  // lap kills b3
            sRed[p] = d * d;
        }
    }
    __syncthreads();
    if (tid == 0) {
        float s = 0.0f;
        #pragma unroll
        for (int p = 0; p < PTS; ++p) s += sRed[p];
        atomicAdd(out + (is_bd ? 0 : 1), s * (is_bd ? scale_bd : scale_int));
    }
}

extern "C" void kernel_launch(void* const* d_in, const int* in_sizes, int n_in,
                              void* d_out, int out_size, void* d_ws, size_t ws_size,
                              hipStream_t stream) {
    const float* xy_int = (const float*)d_in[0];
    const float* f      = (const float*)d_in[1];
    const float* xy_bd  = (const float*)d_in[2];
    const float* g      = (const float*)d_in[3];
    const float* W0 = (const float*)d_in[4];
    const float* b0 = (const float*)d_in[5];
    const float* W1 = (const float*)d_in[6];
    const float* b1 = (const float*)d_in[7];
    const float* W2 = (const float*)d_in[8];
    const float* b2 = (const float*)d_in[9];
    const float* W3 = (const float*)d_in[10];
    const float* b3 = (const float*)d_in[11];
    float* out = (float*)d_out;
    unsigned short* ws = (unsigned short*)d_ws;   // needs 256 KB

    const int n_int = in_sizes[0] / 2;   // 262144
    const int n_bd  = in_sizes[2] / 2;   // 16384

    prep_w_kernel<<<16, 256, 0, stream>>>(W1, W2, ws, out);

    const int smem = (4 * 32 * KP) * 2 + PTS * 4;  // 34,944 B -> 4 blocks/CU
    const int gi = n_int / PTS;
    const int gb = n_bd / PTS;

    pinn_mfma_kernel<<<gi + gb, 256, smem, stream>>>(
        xy_int, f, xy_bd, g, W0, b0, b1, b2, W3, b3, ws, out,
        gi, 0.5f / (float)n_int, 0.5f / (float)n_bd);
}

// Round 12
// 215.566 us; speedup vs baseline: 1.5277x; 1.0594x over previous
//
#include <hip/hip_runtime.h>

#define HID 128
#define PTS 32
#define KP  136   // sB k-row stride in bf16 units (128 + 8 pad; rows 272B = 16B-aligned)
#define FRAGS_PER_W 2048           // 4 mw * 8 ks8 * 64 lanes
#define WS_ELEMS (FRAGS_PER_W * 8) // ushorts per (w, hi/lo) plane

typedef float v4f  __attribute__((ext_vector_type(4)));
typedef float v16f __attribute__((ext_vector_type(16)));
typedef short s8v  __attribute__((ext_vector_type(8)));         // 8 bf16 (MFMA A/B frag)

__device__ __forceinline__ unsigned short f2bf(float f) {       // RNE (prep only)
    unsigned u = __builtin_bit_cast(unsigned, f);
    u = (u + 0x7FFFu + ((u >> 16) & 1u)) >> 16;
    return (unsigned short)u;
}
__device__ __forceinline__ float bf2f(unsigned short h) {
    unsigned u = ((unsigned)h) << 16;
    return __builtin_bit_cast(float, u);
}

// --- packed fp32 -> 2x bf16 (RNE), 1 instr on gfx950 ---
#if __has_builtin(__builtin_amdgcn_cvt_pk_bf16_f32)
typedef __bf16 bf16x2 __attribute__((ext_vector_type(2)));
__device__ __forceinline__ unsigned pk2(float f0, float f1) {   // (bf(f1)<<16)|bf(f0)
    return __builtin_bit_cast(unsigned, __builtin_amdgcn_cvt_pk_bf16_f32(f0, f1));
}
#else
__device__ __forceinline__ unsigned pk2(float f0, float f1) {
    unsigned u0 = __builtin_bit_cast(unsigned, f0);
    unsigned u1 = __builtin_bit_cast(unsigned, f1);
    u0 += 0x7FFFu + ((u0 >> 16) & 1u);
    u1 += 0x7FFFu + ((u1 >> 16) & 1u);
    return __builtin_amdgcn_perm(u1, u0, 0x07060302u);
}
#endif
__device__ __forceinline__ uint2 pk4(const float* f) {
    uint2 h;
    h.x = pk2(f[0], f[1]);
    h.y = pk2(f[2], f[3]);
    return h;
}

// tanh(x) = 1 - 2/(exp(2x)+1); single mul + v_exp + v_rcp
__device__ __forceinline__ float fast_tanh(float x) {
#if __has_builtin(__builtin_amdgcn_exp2f)
    float e = __builtin_amdgcn_exp2f(x * 2.885390081777927f);   // 2*log2(e)
#else
    float e = __expf(2.0f * x);
#endif
    float r = __builtin_amdgcn_rcpf(e + 1.0f);
    return 1.0f - 2.0f * r;
}

// One-time: W1/W2 -> RNE-split bf16 A-fragments for 32x32x16, frag-linear in d_ws.
// A[m][k] = W[k][m]; m = mw*32 + (lane&31), k = ks8*16 + (lane>>5)*8 + i.
// frag idx r = mw*512 + ks8*64 + lane. Planes: [W1hi][W1lo][W2hi][W2lo].
__global__ __launch_bounds__(256) void prep_w_kernel(
    const float* __restrict__ W1, const float* __restrict__ W2,
    unsigned short* __restrict__ ws, float* __restrict__ out)
{
    if (blockIdx.x == 0 && threadIdx.x < 2) out[threadIdx.x] = 0.0f;
    const int t = blockIdx.x * 256 + threadIdx.x;   // 0..4095
    const int w = t >> 11;
    const int r = t & 2047;
    const int mw = r >> 9;
    const int ks8 = (r >> 6) & 7;
    const int lane = r & 63;
    const int m = mw * 32 + (lane & 31);
    const int kb = ks8 * 16 + (lane >> 5) * 8;
    const float* W = w ? W2 : W1;
    s8v hv, lv;
    #pragma unroll
    for (int i = 0; i < 8; ++i) {
        float f = W[(kb + i) * HID + m];
        unsigned short hh = f2bf(f);
        hv[i] = (short)hh;
        lv[i] = (short)f2bf(f - bf2f(hh));
    }
    *(s8v*)&ws[((size_t)(w * 2 + 0) * FRAGS_PER_W + r) * 8] = hv;
    *(s8v*)&ws[((size_t)(w * 2 + 1) * FRAGS_PER_W + r) * 8] = lv;
}

// Round-7/11 structure, GEMM switched to 32x32x16 MFMA: -17% MFMA cycles, and
// each W-prefetch batch (4 loads) is covered by 16 MFMA (~128 cyc) instead of 8
// (~40) -- attacks the ~40% idle from L2 latency. W dbuf shrinks 64->32 VGPR.
// One block = 32 points, 4 channels (0=val,1=dx,2=dy,3=lap). Each wave owns
// m-tile mw (32 j-rows) x ALL 128 n-cols (4 n-tiles == 4 channels).
// C/D (m101): col=lane&31 (=point p), row=(reg&3)+8*(reg>>2)+4*(lane>>5) (=j)
// -> every lane holds all 4 channels of one point: lane-local epilogue.
// 2-product split-bf16 (W=hi+lo exact to 2^-18); activations RNE bf16 in LDS.
__global__ __launch_bounds__(256, 4) void pinn_mfma_kernel(
    const float* __restrict__ xy_int, const float* __restrict__ f_t,
    const float* __restrict__ xy_bd, const float* __restrict__ g_t,
    const float* __restrict__ W0, const float* __restrict__ b0,
    const float* __restrict__ b1, const float* __restrict__ b2,
    const float* __restrict__ W3, const float* __restrict__ b3,
    const unsigned short* __restrict__ ws, float* __restrict__ out,
    int gi, float scale_int, float scale_bd)
{
    extern __shared__ char smem_raw[];
    unsigned short* sBh = (unsigned short*)smem_raw;     // [4*32][KP] bf16 (RNE)
    float* sRed = (float*)(sBh + 4 * 32 * KP);           // [PTS]

    const bool is_bd = (int)blockIdx.x >= gi;
    const float* __restrict__ xy  = is_bd ? xy_bd : xy_int;
    const float* __restrict__ tgt = is_bd ? g_t : f_t;
    const int rc = is_bd ? 0 : 3;                        // readout channel
    const int pbase = (is_bd ? ((int)blockIdx.x - gi) : (int)blockIdx.x) * PTS;

    const int tid  = threadIdx.x;
    const int lane = tid & 63;
    const int mw   = tid >> 6;      // wave = m-tile (32 j-rows)
    const int l31  = lane & 31;
    const int kh   = lane >> 5;     // k-half within frag / j-offset +4*kh in C

    // ---- layer 0: 2 -> 128, VALU, RNE-bf16 store into sB ----
    {
        const int tj = tid & 31, tp = tid >> 5;
        const int j0 = tj * 4, p0 = tp * 4;
        float wx[4], wy[4], bb[4];
        #pragma unroll
        for (int jj = 0; jj < 4; ++jj) {
            wx[jj] = W0[j0 + jj];
            wy[jj] = W0[HID + j0 + jj];
            bb[jj] = b0[j0 + jj];
        }
        #pragma unroll
        for (int pp = 0; pp < 4; ++pp) {
            const int p = p0 + pp;
            const float2 t2 = ((const float2*)xy)[pbase + p];
            float chv[4][4];                    // [c][jj]
            #pragma unroll
            for (int jj = 0; jj < 4; ++jj) {
                float z = fmaf(t2.x, wx[jj], fmaf(t2.y, wy[jj], bb[jj]));
                float a = fast_tanh(z);
                float t = fmaf(-a, a, 1.0f);
                float s2 = fmaf(wx[jj], wx[jj], wy[jj] * wy[jj]);
                chv[0][jj] = a;
                chv[1][jj] = t * wx[jj];
                chv[2][jj] = t * wy[jj];
                chv[3][jj] = -2.0f * a * t * s2;        // z_lap = 0 at layer 0
            }
            #pragma unroll
            for (int c = 0; c < 4; ++c) {
                const int row = (c * 32 + p) * KP + j0;
                *(uint2*)&sBh[row] = pk4(chv[c]);
            }
        }
    }
    __syncthreads();

    // ---- hidden layers: D = (Whi+Wlo)(A-op 32x32) x Act(B-op), 2-product ----
    #pragma unroll
    for (int L = 0; L < 2; ++L) {
        const unsigned short* wshi = ws + (size_t)L * 2 * WS_ELEMS;
        const unsigned short* wslo = wshi + WS_ELEMS;

        // stage = K32 = 2 ks8 sub-frags; double-buffered: 8 s8v = 32 VGPR
        s8v whi[2][2], wlo[2][2];
        #pragma unroll
        for (int h = 0; h < 2; ++h) {
            const int idx = mw * 512 + h * 64 + lane;         // stage 0
            whi[0][h] = *(const s8v*)&wshi[(size_t)idx * 8];
            wlo[0][h] = *(const s8v*)&wslo[(size_t)idx * 8];
        }

        v16f acc[4] = {};   // [ntile == channel]

        #pragma unroll
        for (int s = 0; s < 4; ++s) {
            const int cur = s & 1, nxt = cur ^ 1;
            if (s < 3) {    // prefetch next stage from L2 while 16 MFMAs run
                #pragma unroll
                for (int h = 0; h < 2; ++h) {
                    const int idx = mw * 512 + ((s + 1) * 2 + h) * 64 + lane;
                    whi[nxt][h] = *(const s8v*)&wshi[(size_t)idx * 8];
                    wlo[nxt][h] = *(const s8v*)&wslo[(size_t)idx * 8];
                }
            }
            #pragma unroll
            for (int h = 0; h < 2; ++h) {
                const int koff = (s * 2 + h) * 16 + kh * 8;   // B: k=(lane>>5)*8+i
                #pragma unroll
                for (int nt = 0; nt < 4; ++nt) {
                    s8v bh = *(const s8v*)&sBh[(nt * 32 + l31) * KP + koff];
                    acc[nt] = __builtin_amdgcn_mfma_f32_32x32x16_bf16(
                        whi[cur][h], bh, acc[nt], 0, 0, 0);
                    acc[nt] = __builtin_amdgcn_mfma_f32_32x32x16_bf16(
                        wlo[cur][h], bh, acc[nt], 0, 0, 0);
                }
            }
        }
        __syncthreads();            // all waves done reading sB

        const float* __restrict__ bptr = (L == 0) ? b1 : b2;
        #pragma unroll
        for (int g = 0; g < 4; ++g) {       // reg-groups: j = j0g + (r&3)
            const int j0g = mw * 32 + 8 * g + 4 * kh;
            const v4f bb = *(const v4f*)&bptr[j0g];
            float chv[4][4];                // [c][r]
            #pragma unroll
            for (int r = 0; r < 4; ++r) {
                float z = acc[0][g * 4 + r] + bb[r];
                float a = fast_tanh(z);
                float t = fmaf(-a, a, 1.0f);
                float zx = acc[1][g * 4 + r], zy = acc[2][g * 4 + r],
                      zl = acc[3][g * 4 + r];
                float s2 = fmaf(zx, zx, zy * zy);
                chv[0][r] = a;
                chv[1][r] = t * zx;
                chv[2][r] = t * zy;
                chv[3][r] = fmaf(t, zl, -2.0f * a * t * s2);
            }
            #pragma unroll
            for (int c = 0; c < 4; ++c) {
                if (L == 1 && c != rc) continue;    // uniform: skip dead conv+store
                const int row = (c * 32 + l31) * KP + j0g;
                *(uint2*)&sBh[row] = pk4(chv[c]);
            }
        }
        __syncthreads();
    }

    // ---- readout: dot with W3 over k, 8 lanes per point ----
    {
        const int p  = tid >> 3;
        const int i  = tid & 7;
        const int k0 = i * 16;
        const int row = (rc * 32 + p) * KP + k0;
        float r = 0.0f;
        #pragma unroll
        for (int h = 0; h < 2; ++h) {
            s8v vh = *(const s8v*)&sBh[row + h * 8];
            #pragma unroll
            for (int t = 0; t < 8; ++t)
                r = fmaf(bf2f((unsigned short)vh[t]), W3[k0 + h * 8 + t], r);
        }
        r += __shfl_xor(r, 1, 64);
        r += __shfl_xor(r, 2, 64);
        r += __shfl_xor(r, 4, 64);
        if (i == 0) {
            float d = r + (is_bd ? b3[0] : 0.0f) - tgt[pbase + p];  // lap kills b3
            sRed[p] = d * d;
        }
    }
    __syncthreads();
    if (tid == 0) {
        float s = 0.0f;
        #pragma unroll
        for (int p = 0; p < PTS; ++p) s += sRed[p];
        atomicAdd(out + (is_bd ? 0 : 1), s * (is_bd ? scale_bd : scale_int));
    }
}

extern "C" void kernel_launch(void* const* d_in, const int* in_sizes, int n_in,
                              void* d_out, int out_size, void* d_ws, size_t ws_size,
                              hipStream_t stream) {
    const float* xy_int = (const float*)d_in[0];
    const float* f      = (const float*)d_in[1];
    const float* xy_bd  = (const float*)d_in[2];
    const float* g      = (const float*)d_in[3];
    const float* W0 = (const float*)d_in[4];
    const float* b0 = (const float*)d_in[5];
    const float* W1 = (const float*)d_in[6];
    const float* b1 = (const float*)d_in[7];
    const float* W2 = (const float*)d_in[8];
    const float* b2 = (const float*)d_in[9];
    const float* W3 = (const float*)d_in[10];
    const float* b3 = (const float*)d_in[11];
    float* out = (float*)d_out;
    unsigned short* ws = (unsigned short*)d_ws;   // needs 256 KB

    const int n_int = in_sizes[0] / 2;   // 262144
    const int n_bd  = in_sizes[2] / 2;   // 16384

    prep_w_kernel<<<16, 256, 0, stream>>>(W1, W2, ws, out);

    const int smem = (4 * 32 * KP) * 2 + PTS * 4;  // 34,944 B -> 4 blocks/CU
    const int gi = n_int / PTS;
    const int gb = n_bd / PTS;

    pinn_mfma_kernel<<<gi + gb, 256, smem, stream>>>(
        xy_int, f, xy_bd, g, W0, b0, b1, b2, W3, b3, ws, out,
        gi, 0.5f / (float)n_int, 0.5f / (float)n_bd);
}